// Round 1
// baseline (377.992 us; speedup 1.0000x reference)
//
#include <hip/hip_runtime.h>
#include <math.h>

#define L_SEQ    8192
#define NFFT     8192      // complex FFT size (packs the 16384-pt real FFT)
#define LOG2N    13
#define NTHREADS 512
#define NB       8
#define NC       256
#define PI_F     3.14159265358979323846f

__device__ __forceinline__ float2 cmul(float2 a, float2 b) {
    return make_float2(fmaf(a.x, b.x, -(a.y * b.y)), fmaf(a.x, b.y, a.y * b.x));
}
__device__ __forceinline__ float2 cadd(float2 a, float2 b) { return make_float2(a.x + b.x, a.y + b.y); }
__device__ __forceinline__ float2 csub(float2 a, float2 b) { return make_float2(a.x - b.x, a.y - b.y); }
__device__ __forceinline__ float2 conj2(float2 a) { return make_float2(a.x, -a.y); }
__device__ __forceinline__ int brev13(unsigned x) { return (int)(__brev(x) >> (32 - LOG2N)); }

// Radix-2 DIF: natural order in, bit-reversed order out. Twiddle exp(-i*pi*j/m).
__device__ __forceinline__ void fft_dif(float2* z, const int tid) {
    for (int m = NFFT / 2; m >= 1; m >>= 1) {
        __syncthreads();
        const float ang = -PI_F / (float)m;
        #pragma unroll
        for (int r = 0; r < (NFFT / 2) / NTHREADS; ++r) {
            const int k  = r * NTHREADS + tid;
            const int j  = k & (m - 1);
            const int i0 = 2 * k - j;
            const int i1 = i0 + m;
            const float2 a = z[i0];
            const float2 b = z[i1];
            float s, cc;
            __sincosf(ang * (float)j, &s, &cc);
            z[i0] = cadd(a, b);
            z[i1] = cmul(csub(a, b), make_float2(cc, s));
        }
    }
    __syncthreads();
}

// Radix-2 DIT inverse (unnormalized): bit-reversed in, natural out. Twiddle exp(+i*pi*j/m).
__device__ __forceinline__ void fft_dit_inv(float2* z, const int tid) {
    for (int m = 1; m <= NFFT / 2; m <<= 1) {
        __syncthreads();
        const float ang = PI_F / (float)m;
        #pragma unroll
        for (int r = 0; r < (NFFT / 2) / NTHREADS; ++r) {
            const int k  = r * NTHREADS + tid;
            const int j  = k & (m - 1);
            const int i0 = 2 * k - j;
            const int i1 = i0 + m;
            const float2 a = z[i0];
            float s, cc;
            __sincosf(ang * (float)j, &s, &cc);
            const float2 b = cmul(z[i1], make_float2(cc, s));
            z[i0] = cadd(a, b);
            z[i1] = csub(a, b);
        }
    }
    __syncthreads();
}

__global__ __launch_bounds__(NTHREADS)
void fftconv_kernel(const float* __restrict__ x,
                    const float* __restrict__ kern,
                    float* __restrict__ out) {
    extern __shared__ float2 z[];   // NFFT complex = 64 KB
    const int tid = threadIdx.x;
    const int c   = blockIdx.x >> 1;     // channel
    const int bh  = blockIdx.x & 1;      // which half of the batch

    // ---------- Phase A: smooth+squash kern row, pack, FFT ----------
    {
        const float* kr = kern + (size_t)c * L_SEQ;
        const int base = tid * 16;
        float v[16];
        #pragma unroll
        for (int e = 0; e < 16; ++e) {
            const int i = base + e;
            float s = 0.f;
            #pragma unroll
            for (int d = -3; d <= 3; ++d) {
                int idx = i + d;
                idx = (idx < 0) ? -idx : idx;                      // reflect left
                idx = (idx >= L_SEQ) ? (2 * L_SEQ - 2 - idx) : idx; // reflect right
                s += kr[idx];
            }
            s *= (1.0f / 7.0f);
            const float a = fabsf(s) - 0.003f;
            v[e] = (a > 0.f) ? copysignf(a, s) : 0.f;
        }
        #pragma unroll
        for (int e = 0; e < 8; ++e)
            z[tid * 8 + e] = make_float2(v[2 * e], v[2 * e + 1]);  // pack even+i*odd
        #pragma unroll
        for (int r = 0; r < 8; ++r)
            z[NFFT / 2 + r * NTHREADS + tid] = make_float2(0.f, 0.f); // zero-pad
    }
    fft_dif(z, tid);

    // Extract rfft bins K[f] (f=0..N/2) and K[N-f] into registers.
    // Statically indexed (full unroll) so kA/kB stay in VGPRs.
    float2 kA[9], kB[9];
    #pragma unroll
    for (int it = 0; it < 9; ++it) {
        const int f = tid + it * NTHREADS;
        if (f <= NFFT / 2) {
            const int g = (NFFT - f) & (NFFT - 1);
            const float2 Zf = z[brev13(f)];
            const float2 Zg = z[brev13(g)];
            float s, cc;
            __sincosf(PI_F * (float)f * (1.0f / NFFT), &s, &cc);
            // E = (Zf + conj(Zg))/2 ; O = (Zf - conj(Zg))/(2i)
            const float2 E = make_float2(0.5f * (Zf.x + Zg.x), 0.5f * (Zf.y - Zg.y));
            const float2 O = make_float2(0.5f * (Zf.y + Zg.y), -0.5f * (Zf.x - Zg.x));
            // R[f] = E + exp(-i*pi*f/N) * O ; R[N-f] = conj(E) + (-exp(+i*pi*f/N))... 
            kA[it] = cadd(E, cmul(make_float2(cc, -s), O));
            kB[it] = cadd(conj2(E), cmul(make_float2(-cc, -s), conj2(O)));
        }
    }

    // ---------- Phase B: 4 batch rows ----------
    for (int bi = 0; bi < 4; ++bi) {
        const int b = bh * 4 + bi;
        __syncthreads();   // previous readers of z are done
        const float2* xr = (const float2*)(x + ((size_t)b * NC + c) * L_SEQ);
        #pragma unroll
        for (int r = 0; r < 8; ++r)
            z[r * NTHREADS + tid] = xr[r * NTHREADS + tid];
        #pragma unroll
        for (int r = 0; r < 8; ++r)
            z[NFFT / 2 + r * NTHREADS + tid] = make_float2(0.f, 0.f);

        fft_dif(z, tid);

        // Pointwise in bit-reversed positions. Each (f, N-f) pair is owned by
        // exactly one thread -> read-modify-write with no barrier.
        #pragma unroll
        for (int it = 0; it < 9; ++it) {
            const int f = tid + it * NTHREADS;
            if (f <= NFFT / 2) {
                const int g  = (NFFT - f) & (NFFT - 1);
                const int pf = brev13(f), pg = brev13(g);
                const float2 Zf = z[pf];
                const float2 Zg = z[pg];
                float s, cc;
                __sincosf(PI_F * (float)f * (1.0f / NFFT), &s, &cc);
                const float2 E = make_float2(0.5f * (Zf.x + Zg.x), 0.5f * (Zf.y - Zg.y));
                const float2 O = make_float2(0.5f * (Zf.y + Zg.y), -0.5f * (Zf.x - Zg.x));
                const float2 Xf = cadd(E, cmul(make_float2(cc, -s), O));
                const float2 Xg = cadd(conj2(E), cmul(make_float2(-cc, -s), conj2(O)));
                // Y = X*K, with 1/N inverse-normalization folded in
                float2 Yf = cmul(Xf, kA[it]);
                float2 Yg = cmul(Xg, kB[it]);
                Yf = make_float2(Yf.x * (1.0f / NFFT), Yf.y * (1.0f / NFFT));
                Yg = make_float2(Yg.x * (1.0f / NFFT), Yg.y * (1.0f / NFFT));
                // W[f] = (Yf + conj(Yg))/2 + i*exp(+i*pi*f/N)*(Yf - conj(Yg))/2
                const float2 P = make_float2(0.5f * (Yf.x + Yg.x), 0.5f * (Yf.y - Yg.y));
                const float2 Q = make_float2(0.5f * (Yf.x - Yg.x), 0.5f * (Yf.y + Yg.y));
                z[pf] = cadd(P, cmul(make_float2(-s, cc), Q));
                if (f != 0) {   // W[N-f]; f==N/2 rewrites same addr with same value (same thread)
                    const float2 Pg = make_float2(P.x, -P.y);
                    const float2 Qg = make_float2(-Q.x, Q.y);
                    z[pg] = cadd(Pg, cmul(make_float2(-s, -cc), Qg));
                }
            }
        }

        fft_dit_inv(z, tid);

        // z[n] = {y[2n], y[2n+1]} in natural order; emit first L_SEQ samples.
        float2* orow = (float2*)(out + ((size_t)b * NC + c) * L_SEQ);
        #pragma unroll
        for (int r = 0; r < 8; ++r)
            orow[r * NTHREADS + tid] = z[r * NTHREADS + tid];
    }
}

extern "C" void kernel_launch(void* const* d_in, const int* in_sizes, int n_in,
                              void* d_out, int out_size, void* d_ws, size_t ws_size,
                              hipStream_t stream) {
    const float* x    = (const float*)d_in[0];
    const float* kern = (const float*)d_in[1];
    float* out        = (float*)d_out;
    const size_t lds_bytes = (size_t)NFFT * sizeof(float2);  // 64 KB
    hipLaunchKernelGGL(fftconv_kernel, dim3(NC * 2), dim3(NTHREADS), lds_bytes, stream,
                       x, kern, out);
}